// Round 9
// baseline (289.027 us; speedup 1.0000x reference)
//
#include <hip/hip_runtime.h>
#include <hip/hip_bf16.h>
#include <math.h>

#define N_NODES   50000
#define N_EDGES   1600000
#define IN_F      128
#define D_ATT     64
#define N_HEADS   8
#define D_HEAD    8
#define RSQRT8    0.35355339059327373f
#define EPS_SM    1e-16f
#define NEH       (N_EDGES * N_HEADS)      // 12.8M (edge,head)
#define LPAD      136                      // LDS row stride (bf16 elems); 272 B
                                           // -> b128 frag reads spread over all 32 banks

// native clang vectors (required by nontemporal builtins / MFMA intrinsics)
typedef float f32x4 __attribute__((ext_vector_type(4)));
typedef short s16x8 __attribute__((ext_vector_type(8)));   // 8 bf16 (4 VGPRs)

__device__ inline unsigned short f2bf(float v) {
    __hip_bfloat16 b = __float2bfloat16(v);
    return *(unsigned short*)&b;
}
__device__ inline float bflo(unsigned u) { return __uint_as_float(u << 16); }
__device__ inline float bfhi(unsigned u) { return __uint_as_float(u & 0xffff0000u); }

// ---------------------------------------------------------------------------
// K0 (new): one-time prep.  Converts Wq/Wk/Wv (3 x 64 x 128 f32) into a
// single bf16 table wb[3][64][128] (48 KB -- L2-hot for K1's fragment
// reads), and zeroes the segment-sum table (moved out of K1's prologue).
// ---------------------------------------------------------------------------
__global__ void k_prep(const float* __restrict__ Wq, const float* __restrict__ Wk,
                       const float* __restrict__ Wv,
                       unsigned short* __restrict__ wb, float* __restrict__ s) {
    int t    = blockIdx.x * blockDim.x + threadIdx.x;
    int nthr = gridDim.x * blockDim.x;
    for (int i = t; i < N_NODES * N_HEADS; i += nthr) s[i] = 0.0f;
    const float* Ws[3] = {Wq, Wk, Wv};
    for (int i = t; i < 3 * D_ATT * IN_F; i += nthr) {
        int mm = i / (D_ATT * IN_F);
        int r  = i - mm * (D_ATT * IN_F);
        wb[i] = f2bf(Ws[mm][r]);
    }
}

// ---------------------------------------------------------------------------
// K1 v3: fused q/k/v projection via bf16 MFMA (16x16x32), f32 accumulate.
// W is NOT staged in LDS: A-fragments read directly from the 48 KB L2-hot
// bf16 table (lane -> 16 B dwordx4 at row ft*16+lane).  LDS holds only the
// X tile (17.4 KB -> 4+ blocks/CU, all 782 blocks co-resident, no tail).
// ZERO barriers: wave w stages exactly X rows 16w..16w+15 (tid>>2 mapping)
// and consumes only those rows -> per-wave lgkmcnt ordering suffices.
// Identical bf16 values + accumulation order as R6/R8 -> bit-identical
// output (absmax canary: 0.0078125).
// ---------------------------------------------------------------------------
__global__ __launch_bounds__(256) void k_proj(
        const float* __restrict__ x,
        const unsigned short* __restrict__ wb,
        const float* __restrict__ bq, const float* __restrict__ bk,
        const float* __restrict__ bv,
        unsigned short* __restrict__ qp, unsigned short* __restrict__ kp,
        float* __restrict__ vout) {
    __shared__ unsigned short Xb[64][LPAD];      // 17.4 KB  [node][k] bf16
    const int tid = threadIdx.x;
    const int n0  = blockIdx.x * 64;

    {   // ---- stage X tile as bf16: thread t -> node t>>2, quarter t&3 ----
        // wave w (tids 64w..64w+63) stages nodes 16w..16w+15 == the rows it reads
        int node = tid >> 2;
        int q4   = tid & 3;
        int n    = n0 + node;
        unsigned short* dst = &Xb[node][q4 * 32];
        if (n < N_NODES) {
            const float4* xr = (const float4*)(x + (size_t)n * IN_F + q4 * 32);
#pragma unroll
            for (int i = 0; i < 8; ++i) {
                float4 v = xr[i];
                *(unsigned*)(dst + i * 4)     = ((unsigned)f2bf(v.y) << 16) | f2bf(v.x);
                *(unsigned*)(dst + i * 4 + 2) = ((unsigned)f2bf(v.w) << 16) | f2bf(v.z);
            }
        } else {
#pragma unroll
            for (int i = 0; i < 16; ++i) ((unsigned*)dst)[i] = 0u;
        }
    }
    // no __syncthreads(): no cross-wave LDS dependency

    const int wv   = tid >> 6;        // wave id -> node subtile
    const int ln   = tid & 63;
    const int lane = ln & 15;         // node (B col) AND feat (A row) index
    const int kgrp = ln >> 4;         // k-group / D-row group
    const int mynode = n0 + wv * 16 + lane;
    const int f0     = kgrp * 4;      // D rows = feats f0..f0+3 within tile

    const float* blist[3] = {bq, bk, bv};

    f32x4 acc[3][4];
#pragma unroll
    for (int mm = 0; mm < 3; ++mm)
#pragma unroll
        for (int ft = 0; ft < 4; ++ft) acc[mm][ft] = (f32x4){0.f, 0.f, 0.f, 0.f};

#pragma unroll
    for (int ks = 0; ks < 4; ++ks) {
        int kof = ks * 32 + kgrp * 8;
        s16x8 xf = *(const s16x8*)&Xb[wv * 16 + lane][kof];
#pragma unroll
        for (int mm = 0; mm < 3; ++mm)
#pragma unroll
            for (int ft = 0; ft < 4; ++ft) {
                s16x8 wf = *(const s16x8*)(wb +
                        ((size_t)(mm * 64 + ft * 16 + lane)) * IN_F + kof);
                acc[mm][ft] = __builtin_amdgcn_mfma_f32_16x16x32_bf16(wf, xf, acc[mm][ft], 0, 0, 0);
            }
    }

    if (mynode < N_NODES) {
#pragma unroll
        for (int mm = 0; mm < 3; ++mm) {
            if (mm < 2) {
                unsigned short* dstp = (mm == 0 ? qp : kp) + (size_t)mynode * 64;
#pragma unroll
                for (int ft = 0; ft < 4; ++ft) {
                    int fb = ft * 16 + f0;
                    float4 bj = *(const float4*)&blist[mm][fb];
                    ushort4 o;
                    o.x = f2bf(acc[mm][ft].x + bj.x);
                    o.y = f2bf(acc[mm][ft].y + bj.y);
                    o.z = f2bf(acc[mm][ft].z + bj.z);
                    o.w = f2bf(acc[mm][ft].w + bj.w);
                    *(ushort4*)(dstp + fb) = o;
                }
            } else {
#pragma unroll
                for (int ft = 0; ft < 4; ++ft) {
                    int fb = ft * 16 + f0;
                    float4 bj = *(const float4*)&blist[mm][fb];
                    float vv[4] = {acc[mm][ft].x + bj.x, acc[mm][ft].y + bj.y,
                                   acc[mm][ft].z + bj.z, acc[mm][ft].w + bj.w};
#pragma unroll
                    for (int j = 0; j < 4; ++j) {
                        int f = fb + j;
                        vout[(size_t)mynode * 64 + (f & 7) * 8 + (f >> 3)] = vv[j];
                    }
                }
            }
        }
    }
}

// ---------------------------------------------------------------------------
// K2 (PROVEN, pinned at ~88 us): prods + exp + segment-sum. 8 threads/edge
// (one per head); each lane reads a contiguous 16 B bf16 q fragment + 16 B
// k fragment (an edge's 8 lanes cover its two 128 B rows exactly ->
// line-minimal gather).  f32 atomicAdd is the fast fire-and-forget L2 path
// (u64 packed atomics regressed 3.2x in R5).  prods store nontemporal.
// No max-subtraction: |logit| <~ 1 (verified absmax history).
// ---------------------------------------------------------------------------
__global__ void k_prods_exp(const int* __restrict__ e0, const int* __restrict__ e1,
                            const float* __restrict__ ea,
                            const unsigned short* __restrict__ qp,
                            const unsigned short* __restrict__ kp,
                            float* __restrict__ prods_out,
                            float* __restrict__ s) {
    int t = blockIdx.x * blockDim.x + threadIdx.x;
    if (t >= NEH) return;
    int e = t >> 3, h = t & 7;
    int src = e0[e];
    int dst = e1[e];
    float w = ea[e] * RSQRT8;
    uint4 qv = *(const uint4*)(qp + (size_t)src * 64 + h * 8);
    uint4 kv = *(const uint4*)(kp + (size_t)dst * 64 + h * 8);
    float dot = bflo(qv.x) * bflo(kv.x) + bfhi(qv.x) * bfhi(kv.x)
              + bflo(qv.y) * bflo(kv.y) + bfhi(qv.y) * bfhi(kv.y)
              + bflo(qv.z) * bflo(kv.z) + bfhi(qv.z) * bfhi(kv.z)
              + bflo(qv.w) * bflo(kv.w) + bfhi(qv.w) * bfhi(kv.w);
    float p = dot * w;
    __builtin_nontemporal_store(p, &prods_out[t]);   // coalesced, streaming
    atomicAdd(&s[(size_t)dst * 8 + h], __expf(p));
}

// ---------------------------------------------------------------------------
// K3 (R6-PROVEN form; R7's 1-thread/edge variant regressed -8 us):
// att = exp(prods) / (s[dst,h] + eps), vectorized float4.
// Thread i handles t = 4i..4i+3: e = i>>1, h0 = 4*(i&1) -> one aligned 16-B
// s gather from the L2-hot table; prods/att as 16-B NT streams.
// ---------------------------------------------------------------------------
__global__ void k_norm(const int* __restrict__ e1,
                       const float* __restrict__ prods,
                       float* __restrict__ att,
                       const float* __restrict__ s) {
    int i = blockIdx.x * blockDim.x + threadIdx.x;
    if (i >= NEH / 4) return;
    int e  = i >> 1;
    int h0 = (i & 1) * 4;
    int dst = e1[e];

    f32x4 pv = __builtin_nontemporal_load(&((const f32x4*)prods)[i]);
    f32x4 sv = *(const f32x4*)(s + (size_t)dst * 8 + h0);

    f32x4 a;
    a.x = __expf(pv.x) / (sv.x + EPS_SM);
    a.y = __expf(pv.y) / (sv.y + EPS_SM);
    a.z = __expf(pv.z) / (sv.z + EPS_SM);
    a.w = __expf(pv.w) / (sv.w + EPS_SM);
    __builtin_nontemporal_store(a, &((f32x4*)att)[i]);
}

extern "C" void kernel_launch(void* const* d_in, const int* in_sizes, int n_in,
                              void* d_out, int out_size, void* d_ws, size_t ws_size,
                              hipStream_t stream) {
    const float* x  = (const float*)d_in[0];
    const float* Wq = (const float*)d_in[1];
    const float* bq = (const float*)d_in[2];
    const float* Wk = (const float*)d_in[3];
    const float* bk = (const float*)d_in[4];
    const float* Wv = (const float*)d_in[5];
    const float* bv = (const float*)d_in[6];
    const float* ea = (const float*)d_in[7];
    const int*   edge = (const int*)d_in[8];
    const int* e0 = edge;
    const int* e1 = edge + N_EDGES;

    float* out   = (float*)d_out;
    float* att   = out;                                  // (E, 8)
    float* vout  = att + (size_t)NEH;                    // (N, 8, 8)
    float* prods = vout + (size_t)N_NODES * D_ATT;       // (E, 8)

    unsigned short* qp = (unsigned short*)d_ws;          // (N, 64) bf16
    unsigned short* kp = qp + (size_t)N_NODES * D_ATT;   // (N, 64) bf16
    float* ssum = (float*)(kp + (size_t)N_NODES * D_ATT);// (N, 8) f32
    unsigned short* wb = (unsigned short*)(ssum + (size_t)N_NODES * N_HEADS); // 48 KB bf16 W

    const int B = 256;

    k_prep<<<1024, B, 0, stream>>>(Wq, Wk, Wv, wb, ssum);

    int nTiles = (N_NODES + 63) / 64;
    k_proj<<<nTiles, 256, 0, stream>>>(x, wb, bq, bk, bv, qp, kp, vout);

    int nEH = NEH;
    k_prods_exp<<<(nEH + B - 1) / B, B, 0, stream>>>(e0, e1, ea, qp, kp,
                                                     prods, ssum);

    int nV = NEH / 4;
    k_norm<<<(nV + B - 1) / B, B, 0, stream>>>(e1, prods, att, ssum);
}

// Round 10
// 267.689 us; speedup vs baseline: 1.0797x; 1.0797x over previous
//
#include <hip/hip_runtime.h>
#include <hip/hip_bf16.h>
#include <math.h>

#define N_NODES   50000
#define N_EDGES   1600000
#define IN_F      128
#define D_ATT     64
#define N_HEADS   8
#define D_HEAD    8
#define RSQRT8    0.35355339059327373f
#define EPS_SM    1e-16f
#define NEH       (N_EDGES * N_HEADS)      // 12.8M (edge,head)
#define LPAD      136                      // LDS row stride (bf16 elems)

// native clang vectors (required by nontemporal builtins / MFMA intrinsics)
typedef float f32x4 __attribute__((ext_vector_type(4)));
typedef short s16x8 __attribute__((ext_vector_type(8)));   // 8 bf16 (4 VGPRs)

__device__ inline unsigned short f2bf(float v) {
    __hip_bfloat16 b = __float2bfloat16(v);
    return *(unsigned short*)&b;
}
__device__ inline float bflo(unsigned u) { return __uint_as_float(u << 16); }
__device__ inline float bfhi(unsigned u) { return __uint_as_float(u & 0xffff0000u); }

// ---------------------------------------------------------------------------
// K1 (R6-PROVEN, best measured config): fused q/k/v projection via bf16 MFMA
// (16x16x32), f32 accumulate, per-matrix W staging (34.8 KB LDS -> 4 blk/CU).
// R8 single-stage was null; R9 W-from-global regressed.  Zeroes ssum.
// Block = 64-node tile, 4 waves; wave w owns nodes [n0+16w, n0+16w+16).
// D = W x X^T: C/D col = lane&15 = node, row = (lane>>4)*4+reg = feat.
// ---------------------------------------------------------------------------
__global__ __launch_bounds__(256) void k_proj(
        const float* __restrict__ x,
        const float* __restrict__ Wq, const float* __restrict__ bq,
        const float* __restrict__ Wk, const float* __restrict__ bk,
        const float* __restrict__ Wv, const float* __restrict__ bv,
        unsigned short* __restrict__ qp, unsigned short* __restrict__ kp,
        float* __restrict__ vout, float* __restrict__ s) {
    __shared__ unsigned short Xb[64][LPAD];   // 17.4 KB  [node][k] bf16
    __shared__ unsigned short Wb[64][LPAD];   // 17.4 KB  [feat][k] bf16
    const int tid = threadIdx.x;
    const int n0  = blockIdx.x * 64;

    // ---- zero segment-sum table (grid-stride; 400K floats) ----
    {
        int nthr = gridDim.x * 256;
        for (int i = blockIdx.x * 256 + tid; i < N_NODES * N_HEADS; i += nthr)
            s[i] = 0.0f;
    }

    {   // ---- stage X tile as bf16: thread t -> node t>>2, quarter t&3 ----
        int node = tid >> 2;
        int q4   = tid & 3;
        int n    = n0 + node;
        unsigned short* dst = &Xb[node][q4 * 32];
        if (n < N_NODES) {
            const float4* xr = (const float4*)(x + (size_t)n * IN_F + q4 * 32);
#pragma unroll
            for (int i = 0; i < 8; ++i) {
                float4 v = xr[i];
                *(unsigned*)(dst + i * 4)     = ((unsigned)f2bf(v.y) << 16) | f2bf(v.x);
                *(unsigned*)(dst + i * 4 + 2) = ((unsigned)f2bf(v.w) << 16) | f2bf(v.z);
            }
        } else {
#pragma unroll
            for (int i = 0; i < 16; ++i) ((unsigned*)dst)[i] = 0u;
        }
    }

    const int wv   = tid >> 6;        // wave id -> node subtile
    const int ln   = tid & 63;
    const int lane = ln & 15;         // node (B col) AND feat (A row) index
    const int kgrp = ln >> 4;         // k-group / D-row group
    const int mynode = n0 + wv * 16 + lane;
    const int f0     = kgrp * 4;      // D rows = feats f0..f0+3 within tile

    const float* Wlist[3] = {Wq, Wk, Wv};
    const float* blist[3] = {bq, bk, bv};

    for (int mm = 0; mm < 3; ++mm) {
        __syncthreads();              // Xb ready / prev-mat reads done
        {   // ---- stage W tile as bf16: thread t -> feat t>>2, quarter t&3 ----
            int feat = tid >> 2;
            int q4   = tid & 3;
            const float4* wr = (const float4*)(Wlist[mm] + (size_t)feat * IN_F + q4 * 32);
            unsigned short* dst = &Wb[feat][q4 * 32];
#pragma unroll
            for (int i = 0; i < 8; ++i) {
                float4 v = wr[i];
                *(unsigned*)(dst + i * 4)     = ((unsigned)f2bf(v.y) << 16) | f2bf(v.x);
                *(unsigned*)(dst + i * 4 + 2) = ((unsigned)f2bf(v.w) << 16) | f2bf(v.z);
            }
        }
        __syncthreads();

        f32x4 acc[4];
#pragma unroll
        for (int ft = 0; ft < 4; ++ft) acc[ft] = (f32x4){0.f, 0.f, 0.f, 0.f};

#pragma unroll
        for (int ks = 0; ks < 4; ++ks) {
            int kof = ks * 32 + kgrp * 8;
            s16x8 xf = *(const s16x8*)&Xb[wv * 16 + lane][kof];
#pragma unroll
            for (int ft = 0; ft < 4; ++ft) {
                s16x8 wf = *(const s16x8*)&Wb[ft * 16 + lane][kof];
                acc[ft] = __builtin_amdgcn_mfma_f32_16x16x32_bf16(wf, xf, acc[ft], 0, 0, 0);
            }
        }

        if (mynode < N_NODES) {
            if (mm < 2) {
                unsigned short* dstp = (mm == 0 ? qp : kp) + (size_t)mynode * 64;
#pragma unroll
                for (int ft = 0; ft < 4; ++ft) {
                    int fb = ft * 16 + f0;
                    float4 bj = *(const float4*)&blist[mm][fb];
                    ushort4 o;
                    o.x = f2bf(acc[ft].x + bj.x);
                    o.y = f2bf(acc[ft].y + bj.y);
                    o.z = f2bf(acc[ft].z + bj.z);
                    o.w = f2bf(acc[ft].w + bj.w);
                    *(ushort4*)(dstp + fb) = o;
                }
            } else {
#pragma unroll
                for (int ft = 0; ft < 4; ++ft) {
                    int fb = ft * 16 + f0;
                    float4 bj = *(const float4*)&blist[mm][fb];
                    float vv[4] = {acc[ft].x + bj.x, acc[ft].y + bj.y,
                                   acc[ft].z + bj.z, acc[ft].w + bj.w};
#pragma unroll
                    for (int j = 0; j < 4; ++j) {
                        int f = fb + j;
                        vout[(size_t)mynode * 64 + (f & 7) * 8 + (f >> 3)] = vv[j];
                    }
                }
            }
        }
    }
}

// ---------------------------------------------------------------------------
// K2 (proven ~88 us): prods + exp + segment-sum. 8 threads/edge.
// CHANGE vs R6: prods store is PLAIN (not nontemporal).  prods is NOT a
// pure stream -- K3 re-reads it one dispatch later.  NT was pushing 51.2 MB
// past L2/L3 to HBM; a plain store lets the 256 MB Infinity Cache hold the
// producer->consumer round-trip.
// ---------------------------------------------------------------------------
__global__ void k_prods_exp(const int* __restrict__ e0, const int* __restrict__ e1,
                            const float* __restrict__ ea,
                            const unsigned short* __restrict__ qp,
                            const unsigned short* __restrict__ kp,
                            float* __restrict__ prods_out,
                            float* __restrict__ s) {
    int t = blockIdx.x * blockDim.x + threadIdx.x;
    if (t >= NEH) return;
    int e = t >> 3, h = t & 7;
    int src = e0[e];
    int dst = e1[e];
    float w = ea[e] * RSQRT8;
    uint4 qv = *(const uint4*)(qp + (size_t)src * 64 + h * 8);
    uint4 kv = *(const uint4*)(kp + (size_t)dst * 64 + h * 8);
    float dot = bflo(qv.x) * bflo(kv.x) + bfhi(qv.x) * bfhi(kv.x)
              + bflo(qv.y) * bflo(kv.y) + bfhi(qv.y) * bfhi(kv.y)
              + bflo(qv.z) * bflo(kv.z) + bfhi(qv.z) * bfhi(kv.z)
              + bflo(qv.w) * bflo(kv.w) + bfhi(qv.w) * bfhi(kv.w);
    float p = dot * w;
    prods_out[t] = p;                                // PLAIN: L3 keeps it for K3
    atomicAdd(&s[(size_t)dst * 8 + h], __expf(p));
}

// ---------------------------------------------------------------------------
// K3 (R6 thread mapping): att = exp(prods) / (s[dst,h] + eps), f32x4.
// CHANGE vs R6: prods load is PLAIN cached (L3-hot after K2).  att store
// stays nontemporal -- it is a true pure output, never re-read.
// ---------------------------------------------------------------------------
__global__ void k_norm(const int* __restrict__ e1,
                       const float* __restrict__ prods,
                       float* __restrict__ att,
                       const float* __restrict__ s) {
    int i = blockIdx.x * blockDim.x + threadIdx.x;
    if (i >= NEH / 4) return;
    int e  = i >> 1;
    int h0 = (i & 1) * 4;
    int dst = e1[e];

    f32x4 pv = ((const f32x4*)prods)[i];             // PLAIN: L3 hit
    f32x4 sv = *(const f32x4*)(s + (size_t)dst * 8 + h0);

    f32x4 a;
    a.x = __expf(pv.x) / (sv.x + EPS_SM);
    a.y = __expf(pv.y) / (sv.y + EPS_SM);
    a.z = __expf(pv.z) / (sv.z + EPS_SM);
    a.w = __expf(pv.w) / (sv.w + EPS_SM);
    __builtin_nontemporal_store(a, &((f32x4*)att)[i]);
}

extern "C" void kernel_launch(void* const* d_in, const int* in_sizes, int n_in,
                              void* d_out, int out_size, void* d_ws, size_t ws_size,
                              hipStream_t stream) {
    const float* x  = (const float*)d_in[0];
    const float* Wq = (const float*)d_in[1];
    const float* bq = (const float*)d_in[2];
    const float* Wk = (const float*)d_in[3];
    const float* bk = (const float*)d_in[4];
    const float* Wv = (const float*)d_in[5];
    const float* bv = (const float*)d_in[6];
    const float* ea = (const float*)d_in[7];
    const int*   edge = (const int*)d_in[8];
    const int* e0 = edge;
    const int* e1 = edge + N_EDGES;

    float* out   = (float*)d_out;
    float* att   = out;                                  // (E, 8)
    float* vout  = att + (size_t)NEH;                    // (N, 8, 8)
    float* prods = vout + (size_t)N_NODES * D_ATT;       // (E, 8)

    unsigned short* qp = (unsigned short*)d_ws;          // (N, 64) bf16
    unsigned short* kp = qp + (size_t)N_NODES * D_ATT;   // (N, 64) bf16
    float* ssum = (float*)(kp + (size_t)N_NODES * D_ATT);// (N, 8) f32

    const int B = 256;
    int nTiles = (N_NODES + 63) / 64;
    k_proj<<<nTiles, 256, 0, stream>>>(x, Wq, bq, Wk, bk, Wv, bv,
                                       qp, kp, vout, ssum);

    int nEH = NEH;
    k_prods_exp<<<(nEH + B - 1) / B, B, 0, stream>>>(e0, e1, ea, qp, kp,
                                                     prods, ssum);

    int nV = NEH / 4;
    k_norm<<<(nV + B - 1) / B, B, 0, stream>>>(e1, prods, att, ssum);
}